// Round 18
// baseline (139.507 us; speedup 1.0000x reference)
//
#include <hip/hip_runtime.h>

// VQ-VAE vector quantizer: B=32768, K=4096, D=256 (fp32)
// out = [quantized (B*D floats), vq_loss (1 float)]
//
//  econv_en2: E -> NEGATED fp16 (hi only) per-(ct,q,kb) 4KB frag tiles in ws,
//             fused en2f[k] = 0.5||e||^2 + 512 (bias prefolded)
//  dist17 : dist15 geometry (4 waves x 64r x 64c, X+en2 LDS-resident, packed-u32
//           top-2) with R8's E path: E frags stream global->REGISTER (bv[2][4]
//           parity dbuf, compiler-counted vmcnt) -- no E LDS staging at all.
//           LDS 48KB (X 32 + en2 16, read-only after prologue barrier).
//  rescore: fp64 rescore of 4 candidates; grid 2048 (4 rows/wave)
//  finalize: loss = 1.25 * mean((x-q)^2)

#define B_N 32768
#define K_N 4096
#define D_N 256

typedef _Float16 f16x8 __attribute__((ext_vector_type(8)));
typedef float f32x4 __attribute__((ext_vector_type(4)));
typedef unsigned int uint4v __attribute__((ext_vector_type(4)));
typedef unsigned short u16;

// ws layout (~3.1 MB)
static constexpr size_t P_TOP2 = 0;                               // 32768*2*16 = 1 MB
static constexpr size_t P_ESW  = (size_t)B_N * 2 * 16;            // +2 MB
static constexpr size_t P_EN2  = P_ESW + (size_t)K_N * D_N * 2;   // +16 KB
static constexpr size_t P_PART = P_EN2 + (size_t)K_N * 4;         // +16 KB (2048 doubles)

__device__ __forceinline__ u16 f2h(float f) {
    _Float16 h = (_Float16)f;
    return __builtin_bit_cast(u16, h);
}

__device__ __forceinline__ void gload_lds16(const void* g, void* l) {
    __builtin_amdgcn_global_load_lds(
        (const __attribute__((address_space(1))) void*)g,
        (__attribute__((address_space(3))) void*)l, 16, 0, 0);
}

__device__ __forceinline__ void top2_merge(float& v0, int& i0, float& v1, int& i1,
                                           float ov0, int oi0, float ov1, int oi1) {
    bool bf_ = (ov0 < v0) || (ov0 == v0 && oi0 < i0);
    float w0v = bf_ ? ov0 : v0;  int w0i = bf_ ? oi0 : i0;
    float lv  = bf_ ? v0  : ov0; int li  = bf_ ? i0  : oi0;
    float cv  = bf_ ? ov1 : v1;  int ci  = bf_ ? oi1 : i1;
    bool tl = (lv < cv) || (lv == cv && li < ci);
    v0 = w0v; i0 = w0i;
    v1 = tl ? lv : cv; i1 = tl ? li : ci;
}

// ---------- econv_en2: E -> negated fp16 hi frags + fused 0.5||e||^2+512 ----------
// code = ct*256 + q*64 + cf*16 + llo ; d = kb*32 + lhi*8 + j
// Esw u16 idx = (((ct*4+q)*8+kb)*4 + cf)*512 + (lhi*16+llo)*8
// en2f[code] = 0.5*||e||^2 + 512
__global__ void econv_en2_kernel(const float* __restrict__ E, u16* __restrict__ Esw,
                                 float* __restrict__ en2f) {
    const int gid = blockIdx.x * 256 + threadIdx.x;     // K_N*32 threads
    const int code = gid >> 5;
    const int d0  = (gid & 31) << 3;
    const float4 a = *reinterpret_cast<const float4*>(E + (size_t)code * D_N + d0);
    const float4 b = *reinterpret_cast<const float4*>(E + (size_t)code * D_N + d0 + 4);
    float f[8] = {a.x, a.y, a.z, a.w, b.x, b.y, b.z, b.w};
    unsigned hi[8];
    double ss = 0.0;
    #pragma unroll
    for (int j = 0; j < 8; ++j) {
        hi[j] = f2h(-f[j]);
        ss += (double)f[j] * f[j];
    }
    const int ct = code >> 8, q = (code >> 6) & 3, cf = (code >> 4) & 3, llo = code & 15;
    const int kb = d0 >> 5, lhi = (d0 & 31) >> 3, lane = lhi * 16 + llo;
    size_t base = ((size_t)(((ct * 4 + q) * 8 + kb) * 4 + cf)) * 512 + (size_t)lane * 8;
    uint4v hv;
    hv.x = hi[0] | (hi[1] << 16); hv.y = hi[2] | (hi[3] << 16);
    hv.z = hi[4] | (hi[5] << 16); hv.w = hi[6] | (hi[7] << 16);
    *reinterpret_cast<uint4v*>(Esw + base) = hv;
    // reduce ||e||^2 over the 32 threads of this code (stays within 32-lane half)
    #pragma unroll
    for (int o = 16; o; o >>= 1) ss += __shfl_xor(ss, o, 64);
    if ((gid & 31) == 0) en2f[code] = (float)(0.5 * ss) + 512.0f;
}

// ---------- dist17: dist15 geometry + E global->register streaming ----------
// 512 blocks, 256 thr = 4 waves (q = code quarter), wave tile 64 rows x 64 codes.
// LDS 49152 B: X fp16 [kb8][rf4][lane64][8]u16 @0 (32KB) ;
//              en2 fp32[4096] @32768 (16KB, bias prefolded). Both read-only.
// E: per phase (ct,kb), wave q loads 4 frags from
//    Esw + ct*131072 + q*32768 + kb*4096 + j*1024 + lane*16 into bv parity dbuf.
__launch_bounds__(256, 2)
__global__ void dist17_kernel(const float* __restrict__ X, const char* __restrict__ Esw,
                              const float* __restrict__ en2f, float4* __restrict__ top2) {
    __shared__ __align__(16) char lds[49152];
    const int tid  = threadIdx.x;
    const int lane = tid & 63;
    const int wid  = tid >> 6;          // 0..3 = code quarter q
    const int llo  = lane & 15, lhi = lane >> 4;
    const int rb = blockIdx.x;          // 0..511 (64-row group)

    const char* ep = Esw + (size_t)wid * 32768 + (size_t)lane * 16;

    unsigned pm0[16], pm1[16];          // packed (biased-val-bits & ~63) | (ct*4+j)
    #pragma unroll
    for (int s = 0; s < 16; ++s) { pm0[s] = 0xFFFFFFFFu; pm1[s] = 0xFFFFFFFFu; }

    f32x4 acc[4][4];
    #pragma unroll
    for (int i = 0; i < 4; ++i)
        #pragma unroll
        for (int j = 0; j < 4; ++j) acc[i][j] = (f32x4){0.f, 0.f, 0.f, 0.f};

    // ---- prologue ----
    // X fp32 -> fp16 frag layout, dst-ordered: slot s = it*256+tid -> frag f=it*4+wid,
    // lane; consecutive tid write consecutive 16B -> conflict-free ds_write.
    const float* xb = X + (size_t)rb * 64 * D_N;
    #pragma unroll
    for (int it = 0; it < 8; ++it) {
        const int f  = it * 4 + wid;        // 0..31
        const int kb = f >> 2, rf = f & 3;
        const int row = rf * 16 + llo;
        const int d0  = kb * 32 + lhi * 8;
        const float4 a = *reinterpret_cast<const float4*>(xb + (size_t)row * D_N + d0);
        const float4 b = *reinterpret_cast<const float4*>(xb + (size_t)row * D_N + d0 + 4);
        float fv[8] = {a.x, a.y, a.z, a.w, b.x, b.y, b.z, b.w};
        uint4v w;
        w.x = f2h(fv[0]) | ((unsigned)f2h(fv[1]) << 16);
        w.y = f2h(fv[2]) | ((unsigned)f2h(fv[3]) << 16);
        w.z = f2h(fv[4]) | ((unsigned)f2h(fv[5]) << 16);
        w.w = f2h(fv[6]) | ((unsigned)f2h(fv[7]) << 16);
        *reinterpret_cast<uint4v*>(lds + (size_t)(it * 256 + tid) * 16) = w;
    }
    // en2 table (16KB, bias prefolded) via global_load_lds
    const char* en2c = reinterpret_cast<const char*>(en2f);
    #pragma unroll
    for (int it = 0; it < 4; ++it)
        gload_lds16(en2c + it * 4096 + tid * 16, lds + 32768 + it * 4096 + wid * 1024);
    // first E phase (ct=0, kb=0) into parity 0
    f16x8 bv[2][4];
    #pragma unroll
    for (int j = 0; j < 4; ++j)
        bv[0][j] = *reinterpret_cast<const f16x8*>(ep + j * 1024);
    __syncthreads();    // drains ds_writes + vmcnt; X/en2 visible (bv waits auto)

    const f16x8* LX = reinterpret_cast<const f16x8*>(lds);
    const float* ENL = reinterpret_cast<const float*>(lds + 32768);

    for (int ct = 0; ct < 16; ++ct) {
        float en[4];
        #pragma unroll
        for (int j = 0; j < 4; ++j)
            en[j] = ENL[ct * 256 + wid * 64 + j * 16 + llo];   // bias prefolded

        #pragma unroll
        for (int kb = 0; kb < 8; ++kb) {
            const int p = ct * 8 + kb;
            // prefetch next phase's E frags into the other parity buffer
            if (p < 127) {
                const int np = p + 1;
                const int nct = np >> 3, nkb = np & 7;
                const char* es = ep + (size_t)nct * 131072 + (size_t)nkb * 4096;
                #pragma unroll
                for (int j = 0; j < 4; ++j)
                    bv[(kb + 1) & 1][j] = *reinterpret_cast<const f16x8*>(es + j * 1024);
            }

            __builtin_amdgcn_s_setprio(1);
            f16x8 av[4];
            #pragma unroll
            for (int i = 0; i < 4; ++i)
                av[i] = LX[(kb * 4 + i) * 64 + lane];
            #pragma unroll
            for (int i = 0; i < 4; ++i)
                #pragma unroll
                for (int j = 0; j < 4; ++j)
                    acc[i][j] = __builtin_amdgcn_mfma_f32_16x16x32_f16(
                        av[i], bv[kb & 1][j], acc[i][j], 0, 0, 0);
            __builtin_amdgcn_s_setprio(0);

            if (kb == 7) {
                // packed top-2 update: 6 VALU per candidate
                #pragma unroll
                for (int i = 0; i < 4; ++i) {
                    #pragma unroll
                    for (int r = 0; r < 4; ++r) {
                        const int s = i * 4 + r;
                        #pragma unroll
                        for (int j = 0; j < 4; ++j) {
                            const float v = en[j] + acc[i][j][r];
                            const unsigned c =
                                (__float_as_uint(v) & 0xFFFFFFC0u) | (unsigned)(ct * 4 + j);
                            const unsigned loser = pm0[s] > c ? pm0[s] : c;
                            pm0[s] = pm0[s] < c ? pm0[s] : c;
                            pm1[s] = pm1[s] < loser ? pm1[s] : loser;
                        }
                    }
                }
                #pragma unroll
                for (int i = 0; i < 4; ++i)
                    #pragma unroll
                    for (int j = 0; j < 4; ++j) acc[i][j] = (f32x4){0.f, 0.f, 0.f, 0.f};
            }
        }
    }

    // decode packed -> (biased val, global idx)
    float tv0[16], tv1[16];
    int   tpk[16];
    #pragma unroll
    for (int s = 0; s < 16; ++s) {
        const unsigned a = pm0[s], b = pm1[s];
        const int t0 = (int)(a & 63u), t1 = (int)(b & 63u);
        tv0[s] = __uint_as_float(a & 0xFFFFFFC0u);
        tv1[s] = __uint_as_float(b & 0xFFFFFFC0u);
        const int g0 = (t0 >> 2) * 256 + wid * 64 + (t0 & 3) * 16 + llo;
        const int g1 = (t1 >> 2) * 256 + wid * 64 + (t1 & 3) * 16 + llo;
        tpk[s] = (g1 << 16) | g0;
    }

    // merge the 16 column-lanes (llo) via shfl butterfly
    #pragma unroll
    for (int m = 1; m <= 8; m <<= 1) {
        #pragma unroll
        for (int s = 0; s < 16; ++s) {
            float ov0 = __shfl_xor(tv0[s], m, 64);
            float ov1 = __shfl_xor(tv1[s], m, 64);
            int   opk = __shfl_xor(tpk[s], m, 64);
            float v0 = tv0[s], v1 = tv1[s];
            int i0 = tpk[s] & 0xffff, i1 = (tpk[s] >> 16) & 0xffff;
            top2_merge(v0, i0, v1, i1, ov0, opk & 0xffff, ov1, (opk >> 16) & 0xffff);
            tv0[s] = v0; tv1[s] = v1; tpk[s] = (i1 << 16) | i0;
        }
    }

    __syncthreads();
    float4* M = reinterpret_cast<float4*>(lds);   // [64 rows][4 q] (reuses X region)
    if (llo == 0) {
        #pragma unroll
        for (int i = 0; i < 4; ++i)
            #pragma unroll
            for (int r = 0; r < 4; ++r) {
                const int rowl = i * 16 + lhi * 4 + r;
                const int s = i * 4 + r;
                M[rowl * 4 + wid] = make_float4(tv0[s], __int_as_float(tpk[s] & 0xffff),
                                                tv1[s], __int_as_float((tpk[s] >> 16) & 0xffff));
            }
    }
    __syncthreads();
    if (tid < 64) {
        // pairwise merge: waves 0+1 -> entry 0, waves 2+3 -> entry 1
        #pragma unroll
        for (int h = 0; h < 2; ++h) {
            float4 A4 = M[tid * 4 + 2 * h], B4 = M[tid * 4 + 2 * h + 1];
            float v0 = A4.x, v1 = A4.z;
            int i0 = __float_as_int(A4.y), i1 = __float_as_int(A4.w);
            top2_merge(v0, i0, v1, i1, B4.x, __float_as_int(B4.y), B4.z, __float_as_int(B4.w));
            top2[(size_t)(rb * 64 + tid) * 2 + h] =
                make_float4(v0, __int_as_float(i0), v1, __int_as_float(i1));
        }
    }
}

// ---------- rescore: fp64 rescore of 4 candidates, 2048 blocks (4 rows/wave) ----------
__global__ void rescore_kernel(const float* __restrict__ X, const float* __restrict__ E,
                               const float4* __restrict__ top2, float* __restrict__ out,
                               double* __restrict__ partials) {
    const int lane = threadIdx.x & 63;
    const int wid  = (blockIdx.x * blockDim.x + threadIdx.x) >> 6;
    const int nw   = (gridDim.x * blockDim.x) >> 6;
    double wloc = 0.0;

    for (int row = wid; row < B_N; row += nw) {
        float4 t0 = top2[(size_t)row * 2 + 0];
        float4 t1 = top2[(size_t)row * 2 + 1];
        int cand[4] = { __float_as_int(t0.y), __float_as_int(t0.w),
                        __float_as_int(t1.y), __float_as_int(t1.w) };
        const float4 xv = *reinterpret_cast<const float4*>(X + (size_t)row * D_N + lane * 4);

        double bestd = 1e300; int besti = 0x7fffffff;
        float4 beste = make_float4(0.f, 0.f, 0.f, 0.f);
        #pragma unroll
        for (int c = 0; c < 4; ++c) {
            const int k = cand[c];
            const float4 ev = *reinterpret_cast<const float4*>(E + (size_t)k * D_N + lane * 4);
            double dx = (double)xv.x - (double)ev.x;
            double dy = (double)xv.y - (double)ev.y;
            double dz = (double)xv.z - (double)ev.z;
            double dw = (double)xv.w - (double)ev.w;
            double s = dx * dx + dy * dy + dz * dz + dw * dw;
            #pragma unroll
            for (int o = 32; o; o >>= 1) s += __shfl_xor(s, o, 64);
            if (s < bestd || (s == bestd && k < besti)) { bestd = s; besti = k; beste = ev; }
        }
        *reinterpret_cast<float4*>(out + (size_t)row * D_N + lane * 4) = beste;
        wloc += bestd;
    }

    __shared__ double bsum[8];
    const int widx = threadIdx.x >> 6;
    if (lane == 0) bsum[widx] = wloc;
    __syncthreads();
    if (threadIdx.x == 0) {
        double s = 0.0;
        for (int w = 0; w < (int)(blockDim.x >> 6); ++w) s += bsum[w];
        partials[blockIdx.x] = s;
    }
}

__global__ void finalize_kernel(const double* __restrict__ partials, int n,
                                float* __restrict__ loss_out) {
    __shared__ double sm[256];
    double s = 0.0;
    for (int i = threadIdx.x; i < n; i += 256) s += partials[i];
    sm[threadIdx.x] = s;
    __syncthreads();
    for (int st = 128; st; st >>= 1) {
        if (threadIdx.x < st) sm[threadIdx.x] += sm[threadIdx.x + st];
        __syncthreads();
    }
    if (threadIdx.x == 0)
        *loss_out = (float)(1.25 * sm[0] / (double)((size_t)B_N * D_N));
}

extern "C" void kernel_launch(void* const* d_in, const int* in_sizes, int n_in,
                              void* d_out, int out_size, void* d_ws, size_t ws_size,
                              hipStream_t stream) {
    const float* X = (const float*)d_in[0];
    const float* E = (const float*)d_in[1];
    float* out = (float*)d_out;
    char* ws = (char*)d_ws;

    float4* top2     = (float4*)(ws + P_TOP2);
    u16*    Esw      = (u16*)(ws + P_ESW);
    float*  en2f     = (float*)(ws + P_EN2);
    double* partials = (double*)(ws + P_PART);

    econv_en2_kernel<<<(K_N * 32) / 256, 256, 0, stream>>>(E, Esw, en2f);
    dist17_kernel<<<B_N / 64, 256, 0, stream>>>(X, (const char*)Esw, en2f, top2);
    rescore_kernel<<<2048, 256, 0, stream>>>(X, E, top2, out, partials);
    finalize_kernel<<<1, 256, 0, stream>>>(partials, 2048, out + (size_t)B_N * D_N);
}

// Round 19
// 123.500 us; speedup vs baseline: 1.1296x; 1.1296x over previous
//
#include <hip/hip_runtime.h>

// VQ-VAE vector quantizer: B=32768, K=4096, D=256 (fp32)
// out = [quantized (B*D floats), vq_loss (1 float)]
//
// CHAMPION CONFIGURATION (R17, 123.7us total):
//  econv_en2: E -> NEGATED fp16 (hi only) per-(ct,q,kb) 4KB frag tiles in ws,
//             fused en2f[k] = 0.5||e||^2 + 512 (bias prefolded)
//  dist15 : barrier-free, X+en2 LDS-resident, E wave-private via global_load_lds
//           2-parity dbuf + counted vmcnt(4), 4 waves x 64r x 64c, packed-u32
//           top-2 epilogue, X fp32->fp16 conversion in-prologue (conflict-free).
//  rescore: fp64 rescore of 4 candidates; grid 2048 (4 rows/wave)
//  finalize: loss = 1.25 * mean((x-q)^2)

#define B_N 32768
#define K_N 4096
#define D_N 256

typedef _Float16 f16x8 __attribute__((ext_vector_type(8)));
typedef float f32x4 __attribute__((ext_vector_type(4)));
typedef unsigned int uint4v __attribute__((ext_vector_type(4)));
typedef unsigned short u16;

// ws layout (~3.1 MB)
static constexpr size_t P_TOP2 = 0;                               // 32768*2*16 = 1 MB
static constexpr size_t P_ESW  = (size_t)B_N * 2 * 16;            // +2 MB
static constexpr size_t P_EN2  = P_ESW + (size_t)K_N * D_N * 2;   // +16 KB
static constexpr size_t P_PART = P_EN2 + (size_t)K_N * 4;         // +16 KB (2048 doubles)

__device__ __forceinline__ u16 f2h(float f) {
    _Float16 h = (_Float16)f;
    return __builtin_bit_cast(u16, h);
}

__device__ __forceinline__ void gload_lds16(const void* g, void* l) {
    __builtin_amdgcn_global_load_lds(
        (const __attribute__((address_space(1))) void*)g,
        (__attribute__((address_space(3))) void*)l, 16, 0, 0);
}

#define WAITVM(N) asm volatile("s_waitcnt vmcnt(" #N ")" ::: "memory")

__device__ __forceinline__ void top2_merge(float& v0, int& i0, float& v1, int& i1,
                                           float ov0, int oi0, float ov1, int oi1) {
    bool bf_ = (ov0 < v0) || (ov0 == v0 && oi0 < i0);
    float w0v = bf_ ? ov0 : v0;  int w0i = bf_ ? oi0 : i0;
    float lv  = bf_ ? v0  : ov0; int li  = bf_ ? i0  : oi0;
    float cv  = bf_ ? ov1 : v1;  int ci  = bf_ ? oi1 : i1;
    bool tl = (lv < cv) || (lv == cv && li < ci);
    v0 = w0v; i0 = w0i;
    v1 = tl ? lv : cv; i1 = tl ? li : ci;
}

// ---------- econv_en2: E -> negated fp16 hi frags + fused 0.5||e||^2+512 ----------
// code = ct*256 + q*64 + cf*16 + llo ; d = kb*32 + lhi*8 + j
// Esw u16 idx = (((ct*4+q)*8+kb)*4 + cf)*512 + (lhi*16+llo)*8   (dist12 layout)
// en2f[code] = 0.5*||e||^2 + 512
__global__ void econv_en2_kernel(const float* __restrict__ E, u16* __restrict__ Esw,
                                 float* __restrict__ en2f) {
    const int gid = blockIdx.x * 256 + threadIdx.x;     // K_N*32 threads
    const int code = gid >> 5;
    const int d0  = (gid & 31) << 3;
    const float4 a = *reinterpret_cast<const float4*>(E + (size_t)code * D_N + d0);
    const float4 b = *reinterpret_cast<const float4*>(E + (size_t)code * D_N + d0 + 4);
    float f[8] = {a.x, a.y, a.z, a.w, b.x, b.y, b.z, b.w};
    unsigned hi[8];
    double ss = 0.0;
    #pragma unroll
    for (int j = 0; j < 8; ++j) {
        hi[j] = f2h(-f[j]);
        ss += (double)f[j] * f[j];
    }
    const int ct = code >> 8, q = (code >> 6) & 3, cf = (code >> 4) & 3, llo = code & 15;
    const int kb = d0 >> 5, lhi = (d0 & 31) >> 3, lane = lhi * 16 + llo;
    size_t base = ((size_t)(((ct * 4 + q) * 8 + kb) * 4 + cf)) * 512 + (size_t)lane * 8;
    uint4v hv;
    hv.x = hi[0] | (hi[1] << 16); hv.y = hi[2] | (hi[3] << 16);
    hv.z = hi[4] | (hi[5] << 16); hv.w = hi[6] | (hi[7] << 16);
    *reinterpret_cast<uint4v*>(Esw + base) = hv;
    // reduce ||e||^2 over the 32 threads of this code (stays within 32-lane half)
    #pragma unroll
    for (int o = 16; o; o >>= 1) ss += __shfl_xor(ss, o, 64);
    if ((gid & 31) == 0) en2f[code] = (float)(0.5 * ss) + 512.0f;
}

// ---------- dist15: barrier-free GEMM + in-prologue X conversion ----------
// 512 blocks, 256 thr = 4 waves (q = code quarter), wave tile 64 rows x 64 codes.
// LDS 81920 B: X fp16 [kb8][rf4][lane64][8]u16 @0 (32KB) ;
//              E stage @32768: wave q at +q*8192, parity buf 4KB each ;
//              en2 fp32[4096] @65536 (16KB, bias prefolded).
__launch_bounds__(256, 2)
__global__ void dist15_kernel(const float* __restrict__ X, const char* __restrict__ Esw,
                              const float* __restrict__ en2f, float4* __restrict__ top2) {
    __shared__ __align__(16) char lds[81920];
    const int tid  = threadIdx.x;
    const int lane = tid & 63;
    const int wid  = tid >> 6;          // 0..3 = code quarter q
    const int llo  = lane & 15, lhi = lane >> 4;
    const int rb = blockIdx.x;          // 0..511 (64-row group)

    char* ldsE = lds + 32768 + wid * 8192;

    auto STAGE_E = [&](int p) {   // stage 4KB tile (ct=p>>3, q=wid, kb=p&7) into parity p&1
        const char* es = Esw + ((size_t)(((p >> 3) * 4 + wid) * 8 + (p & 7))) * 4096;
        char* lb = ldsE + (p & 1) * 4096;
        gload_lds16(es + lane * 16,        lb);
        gload_lds16(es + 1024 + lane * 16, lb + 1024);
        gload_lds16(es + 2048 + lane * 16, lb + 2048);
        gload_lds16(es + 3072 + lane * 16, lb + 3072);
    };

    unsigned pm0[16], pm1[16];          // packed (biased-val-bits & ~63) | (ct*4+j)
    #pragma unroll
    for (int s = 0; s < 16; ++s) { pm0[s] = 0xFFFFFFFFu; pm1[s] = 0xFFFFFFFFu; }

    f32x4 acc[4][4];
    #pragma unroll
    for (int i = 0; i < 4; ++i)
        #pragma unroll
        for (int j = 0; j < 4; ++j) acc[i][j] = (f32x4){0.f, 0.f, 0.f, 0.f};

    // ---- prologue ----
    // X fp32 -> fp16 frag layout, dst-ordered: slot s = it*256+tid -> frag f=it*4+wid,
    // lane; consecutive tid write consecutive 16B -> conflict-free ds_write.
    const float* xb = X + (size_t)rb * 64 * D_N;
    #pragma unroll
    for (int it = 0; it < 8; ++it) {
        const int f  = it * 4 + wid;        // 0..31
        const int kb = f >> 2, rf = f & 3;
        const int row = rf * 16 + llo;
        const int d0  = kb * 32 + lhi * 8;
        const float4 a = *reinterpret_cast<const float4*>(xb + (size_t)row * D_N + d0);
        const float4 b = *reinterpret_cast<const float4*>(xb + (size_t)row * D_N + d0 + 4);
        float fv[8] = {a.x, a.y, a.z, a.w, b.x, b.y, b.z, b.w};
        uint4v w;
        w.x = f2h(fv[0]) | ((unsigned)f2h(fv[1]) << 16);
        w.y = f2h(fv[2]) | ((unsigned)f2h(fv[3]) << 16);
        w.z = f2h(fv[4]) | ((unsigned)f2h(fv[5]) << 16);
        w.w = f2h(fv[6]) | ((unsigned)f2h(fv[7]) << 16);
        *reinterpret_cast<uint4v*>(lds + (size_t)(it * 256 + tid) * 16) = w;
    }
    // en2 table (16KB, bias prefolded) via global_load_lds
    const char* en2c = reinterpret_cast<const char*>(en2f);
    #pragma unroll
    for (int it = 0; it < 4; ++it)
        gload_lds16(en2c + it * 4096 + tid * 16, lds + 65536 + it * 4096 + wid * 1024);
    STAGE_E(0);
    __syncthreads();    // drains ds_writes + vmcnt; X/en2/E0 visible

    const f16x8* LX = reinterpret_cast<const f16x8*>(lds);
    const float* ENL = reinterpret_cast<const float*>(lds + 65536);

    for (int ct = 0; ct < 16; ++ct) {
        float en[4];
        #pragma unroll
        for (int j = 0; j < 4; ++j)
            en[j] = ENL[ct * 256 + wid * 64 + j * 16 + llo];   // bias prefolded

        #pragma unroll
        for (int kb = 0; kb < 8; ++kb) {
            const int p = ct * 8 + kb;
            if (p < 127) { STAGE_E(p + 1); WAITVM(4); }
            else         { WAITVM(0); }

            f16x8 ev[4];
            #pragma unroll
            for (int j = 0; j < 4; ++j)
                ev[j] = *reinterpret_cast<const f16x8*>(
                    ldsE + (p & 1) * 4096 + j * 1024 + lane * 16);

            __builtin_amdgcn_s_setprio(1);
            f16x8 av[4];
            #pragma unroll
            for (int i = 0; i < 4; ++i)
                av[i] = LX[(kb * 4 + i) * 64 + lane];
            #pragma unroll
            for (int i = 0; i < 4; ++i)
                #pragma unroll
                for (int j = 0; j < 4; ++j)
                    acc[i][j] = __builtin_amdgcn_mfma_f32_16x16x32_f16(
                        av[i], ev[j], acc[i][j], 0, 0, 0);
            __builtin_amdgcn_s_setprio(0);

            if (kb == 7) {
                // packed top-2 update: 6 VALU per candidate
                #pragma unroll
                for (int i = 0; i < 4; ++i) {
                    #pragma unroll
                    for (int r = 0; r < 4; ++r) {
                        const int s = i * 4 + r;
                        #pragma unroll
                        for (int j = 0; j < 4; ++j) {
                            const float v = en[j] + acc[i][j][r];
                            const unsigned c =
                                (__float_as_uint(v) & 0xFFFFFFC0u) | (unsigned)(ct * 4 + j);
                            const unsigned loser = pm0[s] > c ? pm0[s] : c;
                            pm0[s] = pm0[s] < c ? pm0[s] : c;
                            pm1[s] = pm1[s] < loser ? pm1[s] : loser;
                        }
                    }
                }
                #pragma unroll
                for (int i = 0; i < 4; ++i)
                    #pragma unroll
                    for (int j = 0; j < 4; ++j) acc[i][j] = (f32x4){0.f, 0.f, 0.f, 0.f};
            }
        }
    }

    // decode packed -> (biased val, global idx)
    float tv0[16], tv1[16];
    int   tpk[16];
    #pragma unroll
    for (int s = 0; s < 16; ++s) {
        const unsigned a = pm0[s], b = pm1[s];
        const int t0 = (int)(a & 63u), t1 = (int)(b & 63u);
        tv0[s] = __uint_as_float(a & 0xFFFFFFC0u);
        tv1[s] = __uint_as_float(b & 0xFFFFFFC0u);
        const int g0 = (t0 >> 2) * 256 + wid * 64 + (t0 & 3) * 16 + llo;
        const int g1 = (t1 >> 2) * 256 + wid * 64 + (t1 & 3) * 16 + llo;
        tpk[s] = (g1 << 16) | g0;
    }

    // merge the 16 column-lanes (llo) via shfl butterfly
    #pragma unroll
    for (int m = 1; m <= 8; m <<= 1) {
        #pragma unroll
        for (int s = 0; s < 16; ++s) {
            float ov0 = __shfl_xor(tv0[s], m, 64);
            float ov1 = __shfl_xor(tv1[s], m, 64);
            int   opk = __shfl_xor(tpk[s], m, 64);
            float v0 = tv0[s], v1 = tv1[s];
            int i0 = tpk[s] & 0xffff, i1 = (tpk[s] >> 16) & 0xffff;
            top2_merge(v0, i0, v1, i1, ov0, opk & 0xffff, ov1, (opk >> 16) & 0xffff);
            tv0[s] = v0; tv1[s] = v1; tpk[s] = (i1 << 16) | i0;
        }
    }

    __syncthreads();
    float4* M = reinterpret_cast<float4*>(lds);   // [64 rows][4 q] (reuses X region)
    if (llo == 0) {
        #pragma unroll
        for (int i = 0; i < 4; ++i)
            #pragma unroll
            for (int r = 0; r < 4; ++r) {
                const int rowl = i * 16 + lhi * 4 + r;
                const int s = i * 4 + r;
                M[rowl * 4 + wid] = make_float4(tv0[s], __int_as_float(tpk[s] & 0xffff),
                                                tv1[s], __int_as_float((tpk[s] >> 16) & 0xffff));
            }
    }
    __syncthreads();
    if (tid < 64) {
        // pairwise merge: waves 0+1 -> entry 0, waves 2+3 -> entry 1
        #pragma unroll
        for (int h = 0; h < 2; ++h) {
            float4 A4 = M[tid * 4 + 2 * h], B4 = M[tid * 4 + 2 * h + 1];
            float v0 = A4.x, v1 = A4.z;
            int i0 = __float_as_int(A4.y), i1 = __float_as_int(A4.w);
            top2_merge(v0, i0, v1, i1, B4.x, __float_as_int(B4.y), B4.z, __float_as_int(B4.w));
            top2[(size_t)(rb * 64 + tid) * 2 + h] =
                make_float4(v0, __int_as_float(i0), v1, __int_as_float(i1));
        }
    }
}

// ---------- rescore: fp64 rescore of 4 candidates, 2048 blocks (4 rows/wave) ----------
__global__ void rescore_kernel(const float* __restrict__ X, const float* __restrict__ E,
                               const float4* __restrict__ top2, float* __restrict__ out,
                               double* __restrict__ partials) {
    const int lane = threadIdx.x & 63;
    const int wid  = (blockIdx.x * blockDim.x + threadIdx.x) >> 6;
    const int nw   = (gridDim.x * blockDim.x) >> 6;
    double wloc = 0.0;

    for (int row = wid; row < B_N; row += nw) {
        float4 t0 = top2[(size_t)row * 2 + 0];
        float4 t1 = top2[(size_t)row * 2 + 1];
        int cand[4] = { __float_as_int(t0.y), __float_as_int(t0.w),
                        __float_as_int(t1.y), __float_as_int(t1.w) };
        const float4 xv = *reinterpret_cast<const float4*>(X + (size_t)row * D_N + lane * 4);

        double bestd = 1e300; int besti = 0x7fffffff;
        float4 beste = make_float4(0.f, 0.f, 0.f, 0.f);
        #pragma unroll
        for (int c = 0; c < 4; ++c) {
            const int k = cand[c];
            const float4 ev = *reinterpret_cast<const float4*>(E + (size_t)k * D_N + lane * 4);
            double dx = (double)xv.x - (double)ev.x;
            double dy = (double)xv.y - (double)ev.y;
            double dz = (double)xv.z - (double)ev.z;
            double dw = (double)xv.w - (double)ev.w;
            double s = dx * dx + dy * dy + dz * dz + dw * dw;
            #pragma unroll
            for (int o = 32; o; o >>= 1) s += __shfl_xor(s, o, 64);
            if (s < bestd || (s == bestd && k < besti)) { bestd = s; besti = k; beste = ev; }
        }
        *reinterpret_cast<float4*>(out + (size_t)row * D_N + lane * 4) = beste;
        wloc += bestd;
    }

    __shared__ double bsum[8];
    const int widx = threadIdx.x >> 6;
    if (lane == 0) bsum[widx] = wloc;
    __syncthreads();
    if (threadIdx.x == 0) {
        double s = 0.0;
        for (int w = 0; w < (int)(blockDim.x >> 6); ++w) s += bsum[w];
        partials[blockIdx.x] = s;
    }
}

__global__ void finalize_kernel(const double* __restrict__ partials, int n,
                                float* __restrict__ loss_out) {
    __shared__ double sm[256];
    double s = 0.0;
    for (int i = threadIdx.x; i < n; i += 256) s += partials[i];
    sm[threadIdx.x] = s;
    __syncthreads();
    for (int st = 128; st; st >>= 1) {
        if (threadIdx.x < st) sm[threadIdx.x] += sm[threadIdx.x + st];
        __syncthreads();
    }
    if (threadIdx.x == 0)
        *loss_out = (float)(1.25 * sm[0] / (double)((size_t)B_N * D_N));
}

extern "C" void kernel_launch(void* const* d_in, const int* in_sizes, int n_in,
                              void* d_out, int out_size, void* d_ws, size_t ws_size,
                              hipStream_t stream) {
    const float* X = (const float*)d_in[0];
    const float* E = (const float*)d_in[1];
    float* out = (float*)d_out;
    char* ws = (char*)d_ws;

    float4* top2     = (float4*)(ws + P_TOP2);
    u16*    Esw      = (u16*)(ws + P_ESW);
    float*  en2f     = (float*)(ws + P_EN2);
    double* partials = (double*)(ws + P_PART);

    econv_en2_kernel<<<(K_N * 32) / 256, 256, 0, stream>>>(E, Esw, en2f);
    dist15_kernel<<<B_N / 64, 256, 0, stream>>>(X, (const char*)Esw, en2f, top2);
    rescore_kernel<<<2048, 256, 0, stream>>>(X, E, top2, out, partials);
    finalize_kernel<<<1, 256, 0, stream>>>(partials, 2048, out + (size_t)B_N * D_N);
}